// Round 8
// baseline (45.230 us; speedup 1.0000x reference)
//
#include <hip/hip_runtime.h>
#include <math.h>

typedef float nfloat4 __attribute__((ext_vector_type(4)));

// ---------------------------------------------------------------------------
// Fast path: H=W=C=256, S=7. Gather-by-tile:
//   grid = 256 tiles (16x16 px of sample-floor space) x 4 channel-slices.
//   Each block stages its (16+1)^2 px x 64ch patch into LDS ONCE
//   (global_load_lds, sequential), scans all proposals to build the list of
//   sample points whose bilinear floor lands in the tile, then serves every
//   point's 4 taps from LDS. Vector-path read traffic: 205 MB -> 76 MB.
// Index/weight math is in contract(off) helpers shared by the membership
// mask and the compute phase -> bit-identical floors (and identical to the
// mul/sub/div op sequence of the JAX reference).
// ---------------------------------------------------------------------------
#define TILE   16
#define TPX    17            // 16 + 1 halo
#define NPIX   289           // 17*17
#define NPIX_PAD 304         // 19 * 16 (4px per wave-instr * 4 waves * 19 iters)
#define CSLICE 64            // channels per slice (4 slices of 256)
#define LREC_CAP 1024

__device__ __forceinline__ void roi_box(const float4 pr, float& x1, float& y1,
                                        float& w, float& h, float& wc, float& hc) {
    #pragma clang fp contract(off)
    x1 = fmaxf(rintf(pr.x), 0.0f);
    y1 = fmaxf(rintf(pr.y), 0.0f);
    const float x2 = fminf(rintf(pr.z), 255.0f);
    const float y2 = fminf(rintf(pr.w), 255.0f);
    w = x2 - x1; h = y2 - y1;
    wc = fmaxf(w - 1.0f, 0.0f); hc = fmaxf(h - 1.0f, 0.0f);
}

__device__ __forceinline__ void roi_sample(float c1, float len, float lenc, int q,
                                           int* f_out, float* w_out) {
    #pragma clang fp contract(off)
    const float tq = ((float)q + 0.5f) / 7.0f;
    const float s  = fminf(fmaxf(tq * len - 0.5f, 0.0f), lenc) + c1;
    const float f  = floorf(s);
    *f_out = (int)f;
    *w_out = s - f;
}

__global__ __launch_bounds__(256) void roi_tile_gather(
    const float* __restrict__ fm,          // [256,256,256]
    const float4* __restrict__ props,      // [nprop]
    float* __restrict__ out,               // [nprop,7,7,256]
    int nprop)
{
    __shared__ float tile[NPIX_PAD * CSLICE];     // 77,824 B
    __shared__ unsigned short lrec[LREC_CAP];     //  2,048 B
    __shared__ int lcnt;

    const int tid  = threadIdx.x;
    const int wid  = tid >> 6;
    const int lane = tid & 63;
    const int bid  = blockIdx.x;
    const int t    = bid >> 2;                    // tile 0..255
    const int cs   = bid & 3;                     // channel slice 0..3
    const int Ax   = (t & 15) * TILE;
    const int Ay   = (t >> 4) * TILE;

    if (tid == 0) lcnt = 0;
    __syncthreads();                              // cheap: nothing in flight yet

    // -- prefetch this thread's proposals to registers BEFORE staging issue --
    float4 pp[4]; int pn[4]; int nl = 0;
    for (int n = tid; n < nprop && nl < 4; n += 256) { pp[nl] = props[n]; pn[nl] = n; ++nl; }
    __builtin_amdgcn_sched_barrier(0);            // keep props loads oldest in vmcnt

    // -- issue staging: global -> LDS direct, 1 KB (4 pixels) per wave-instr --
    typedef const __attribute__((address_space(1))) unsigned int* gp_t;
    typedef __attribute__((address_space(3))) unsigned int* lp_t;
    for (int k = 0; k < 19; ++k) {
        const int pix0 = k * 16 + (wid << 2);     // wave-uniform LDS base pixel
        const int p    = pix0 + (lane >> 4);
        const int ps   = p > 288 ? 288 : p;       // pad lanes: clamped dup
        const int dy   = ps / 17, dx = ps - dy * 17;
        const int py   = min(Ay + dy, 255);
        const int px   = min(Ax + dx, 255);
        const float* src = fm + (size_t)(py * 256 + px) * 256 + cs * CSLICE
                              + ((lane & 15) << 2);
        __builtin_amdgcn_global_load_lds((gp_t)src, (lp_t)&tile[pix0 * CSLICE], 16, 0, 0);
    }

    // -- scan proposals (VALU only, overlaps staging): build point list --
    for (int k = 0; k < nl; ++k) {
        const int n = pn[k];
        float x1, y1, w, h, wc, hc;
        roi_box(pp[k], x1, y1, w, h, wc, hc);
        // sx spans [x1, x1+wc]; floor in tile <=> sx in [Ax, Ax+16)
        if (x1 >= (float)(Ax + TILE) || x1 + wc < (float)Ax) continue;
        if (y1 >= (float)(Ay + TILE) || y1 + hc < (float)Ay) continue;
        int mj = 0, mi = 0;
        #pragma unroll
        for (int j = 0; j < 7; ++j) {
            int f; float wdum;
            roi_sample(x1, w, wc, j, &f, &wdum);
            if ((unsigned)(f - Ax) < (unsigned)TILE) mj |= 1 << j;
        }
        if (!mj) continue;
        #pragma unroll
        for (int i = 0; i < 7; ++i) {
            int f; float wdum;
            roi_sample(y1, h, hc, i, &f, &wdum);
            if ((unsigned)(f - Ay) < (unsigned)TILE) mi |= 1 << i;
        }
        if (!mi) continue;
        const int np = __popc((unsigned)mi) * __popc((unsigned)mj);
        int slot = atomicAdd(&lcnt, np);
        for (int ii = mi; ii; ii &= ii - 1) {
            const int i = __ffs(ii) - 1;
            for (int jj = mj; jj; jj &= jj - 1) {
                const int j = __ffs(jj) - 1;
                if (slot < LREC_CAP)
                    lrec[slot] = (unsigned short)((n << 6) | (i * 7 + j));
                ++slot;
            }
        }
    }

    __syncthreads();   // drains staging (vmcnt) + list writes (lgkm)

    // -- serve points from LDS: 16 lanes per point (64 ch), 4 points/wave --
    const int lc = min(lcnt, LREC_CAP);
    const int cw = (lane & 15) << 2;              // channel word offset
    for (int base = 0; base < lc; base += 16) {
        const int idx = base + (wid << 2) + (lane >> 4);
        if (idx >= lc) break;                     // group-uniform predicate
        const int rec = lrec[idx];
        const int n  = rec >> 6;
        const int ij = rec & 63;
        const int i  = ij / 7, j = ij - i * 7;

        float x1, y1, w, h, wc, hc;
        roi_box(props[n], x1, y1, w, h, wc, hc);
        int fx, fy; float wx, wy;
        roi_sample(x1, w, wc, j, &fx, &wx);
        roi_sample(y1, h, hc, i, &fy, &wy);

        const int lx0 = fx - Ax;
        const int ly0 = fy - Ay;
        const int lx1 = min(fx + 1, 255) - Ax;
        const int ly1 = min(fy + 1, 255) - Ay;

        const nfloat4 v00 = *(const nfloat4*)&tile[(ly0 * TPX + lx0) * CSLICE + cw];
        const nfloat4 v01 = *(const nfloat4*)&tile[(ly0 * TPX + lx1) * CSLICE + cw];
        const nfloat4 v10 = *(const nfloat4*)&tile[(ly1 * TPX + lx0) * CSLICE + cw];
        const nfloat4 v11 = *(const nfloat4*)&tile[(ly1 * TPX + lx1) * CSLICE + cw];

        const float owx = 1.0f - wx, owy = 1.0f - wy;
        nfloat4 r;
        r.x = (v00.x * owx + v01.x * wx) * owy + (v10.x * owx + v11.x * wx) * wy;
        r.y = (v00.y * owx + v01.y * wx) * owy + (v10.y * owx + v11.y * wx) * wy;
        r.z = (v00.z * owx + v01.z * wx) * owy + (v10.z * owx + v11.z * wx) * wy;
        r.w = (v00.w * owx + v01.w * wx) * owy + (v10.w * owx + v11.w * wx) * wy;

        float* dst = out + (size_t)(n * 49 + ij) * 256 + cs * CSLICE + cw;
        __builtin_nontemporal_store(r, (nfloat4*)dst);
    }
}

// ---------------------------------------------------------------------------
// Generic fallback (any S / C multiple of 4): one wave per sample point.
// ---------------------------------------------------------------------------
__global__ __launch_bounds__(256) void roi_align_generic(
    const float* __restrict__ fm,
    const float* __restrict__ props,
    float* __restrict__ out,
    int S, int nprop, int H, int W, int C)
{
    const int wave = (int)((blockIdx.x * blockDim.x + threadIdx.x) >> 6);
    const int lane = threadIdx.x & 63;
    const int total = nprop * S * S;
    if (wave >= total) return;

    const int n  = wave / (S * S);
    const int ij = wave - n * (S * S);
    const int i  = ij / S;
    const int j  = ij - i * S;

    const float4 pr = ((const float4*)props)[n];
    const float x1 = fmaxf(rintf(pr.x), 0.0f);
    const float y1 = fmaxf(rintf(pr.y), 0.0f);
    const float x2 = fminf(rintf(pr.z), (float)(W - 1));
    const float y2 = fminf(rintf(pr.w), (float)(H - 1));
    const float h  = y2 - y1;
    const float w  = x2 - x1;

    const float sy = fminf(fmaxf((((float)i + 0.5f) / (float)S) * h - 0.5f, 0.0f),
                           fmaxf(h - 1.0f, 0.0f)) + y1;
    const float sx = fminf(fmaxf((((float)j + 0.5f) / (float)S) * w - 0.5f, 0.0f),
                           fmaxf(w - 1.0f, 0.0f)) + x1;

    const float y0f = floorf(sy);
    const float x0f = floorf(sx);
    const int y0i = (int)y0f;
    const int x0i = (int)x0f;
    const int y1i = min(y0i + 1, H - 1);
    const int x1i = min(x0i + 1, W - 1);
    const float wy = sy - y0f, owy = 1.0f - wy;
    const float wx = sx - x0f, owx = 1.0f - wx;

    const float4* r00 = (const float4*)(fm + ((size_t)y0i * W + x0i) * C);
    const float4* r01 = (const float4*)(fm + ((size_t)y0i * W + x1i) * C);
    const float4* r10 = (const float4*)(fm + ((size_t)y1i * W + x0i) * C);
    const float4* r11 = (const float4*)(fm + ((size_t)y1i * W + x1i) * C);
    float4* o = (float4*)(out + (size_t)wave * C);

    const int nvec = C >> 2;
    for (int v = lane; v < nvec; v += 64) {
        const float4 v00 = r00[v];
        const float4 v01 = r01[v];
        const float4 v10 = r10[v];
        const float4 v11 = r11[v];
        float4 r;
        r.x = (v00.x * owx + v01.x * wx) * owy + (v10.x * owx + v11.x * wx) * wy;
        r.y = (v00.y * owx + v01.y * wx) * owy + (v10.y * owx + v11.y * wx) * wy;
        r.z = (v00.z * owx + v01.z * wx) * owy + (v10.z * owx + v11.z * wx) * wy;
        r.w = (v00.w * owx + v01.w * wx) * owy + (v10.w * owx + v11.w * wx) * wy;
        o[v] = r;
    }
}

extern "C" void kernel_launch(void* const* d_in, const int* in_sizes, int n_in,
                              void* d_out, int out_size, void* d_ws, size_t ws_size,
                              hipStream_t stream)
{
    const float* fm    = (const float*)d_in[0];   // (1, 256, 256, 256) f32
    const float* props = (const float*)d_in[1];   // (1024, 4) f32
    float* out = (float*)d_out;
    (void)d_ws; (void)ws_size;

    const int H = 256, W = 256, C = 256;
    const int nprop = in_sizes[1] / 4;
    int S = 1;
    {
        const long long per = (long long)nprop * C;
        const long long ss = (long long)out_size / per;
        while ((long long)(S + 1) * (S + 1) <= ss) ++S;
    }

    if (S == 7 && C == 256 && nprop <= 1024) {
        // 256 tiles x 4 channel-slices
        roi_tile_gather<<<1024, 256, 0, stream>>>(fm, (const float4*)props, out, nprop);
    } else {
        const int total_waves = nprop * S * S;
        const int blocks = (total_waves + 3) / 4;
        roi_align_generic<<<blocks, 256, 0, stream>>>(fm, props, out, S, nprop, H, W, C);
    }
}